// Round 8
// baseline (271.287 us; speedup 1.0000x reference)
//
#include <hip/hip_runtime.h>

// RoIBridge: positional-embedding expansion per bbox coordinate, masked by
// obj_vec==1, dense [B*T, 256] fp32 output.
// B=2048, T=128, D=64, IMAGE_SIZE=224.
//
// R8 (single variable vs R7): replace precise OCML sinf/cosf (~25 VALU ops
// each, ~20 us chip-wide — partially exposed beyond the 42 us store stream)
// with hardware v_sin_f32/v_cos_f32 (input in REVOLUTIONS, ISA sec 3):
// fold 1/(2pi) into the per-thread frequency constant, v_fract for range
// reduction, then __builtin_amdgcn_sinf/cosf. 3 VALU ops/element -> ~2.5 us
// VALU, fully hidden under the store stream.
//
// table[pos, i] = sin(pos * 10000^(-floor(i/2)/32)) even i, cos odd i.
// rev = fract(pos * scale/(2pi)); sin(2pi*rev)=sin(pos*scale) (integer-rev
// shift preserves sin and cos). pos <= 224 -> rev arg exact to ~1e-7 rel;
// v_sin abs err ~5e-4; total ~2.5e-3 vs 2e-2 threshold.

#define ROI_ROWS (2048 * 128)   // B*T = 262,144
#define ROI_IMG  224.0f
#define ROWS_PER_WAVE 4         // ILP-4: best config from R3-R5 sweep

typedef float vfloat4 __attribute__((ext_vector_type(4)));

__global__ __launch_bounds__(256) void RoIBridge_kernel(
    const float* __restrict__ bboxs,   // [ROWS*4]
    const int*   __restrict__ objs,    // [ROWS]
    const float* __restrict__ table,   // unused (recomputed in-register)
    vfloat4*     __restrict__ out)     // [ROWS*64] float4s
{
    (void)table;
    const int tid  = blockIdx.x * 256 + threadIdx.x;
    const int wave = tid >> 6;
    const int lane = threadIdx.x & 63;
    const int c    = lane >> 4;        // coord 0..3 (16 lanes each)
    const int d4   = lane & 15;        // float4 within 64-float embedding

    // Per-thread frequency constants, in REVOLUTIONS per unit pos.
    // Lane's 4 elements are i = d4*4 + j; fi = i>>1 = {2d4, 2d4, 2d4+1, 2d4+1}.
    // scale = 10000^(-fi/32) / (2pi) = exp2(-fi * log2(10000)/32) * (1/2pi)
    const float L      = 0.41524101186092029f;   // log2(10000)/32
    const float INV2PI = 0.15915494309189535f;   // 1/(2pi)
    const float fi0 = (float)(d4 * 2);
    const float s0 = exp2f(-fi0 * L) * INV2PI;          // j=0 (sin), j=1 (cos)
    const float s1 = exp2f(-(fi0 + 1.0f) * L) * INV2PI; // j=2 (sin), j=3 (cos)

    const int row0 = wave * ROWS_PER_WAVE;

    // Phase 1: independent input loads up front
    int   obj[ROWS_PER_WAVE];
    float frac[ROWS_PER_WAVE];
#pragma unroll
    for (int r = 0; r < ROWS_PER_WAVE; ++r) {
        obj[r]  = objs[row0 + r];
        frac[r] = bboxs[((row0 + r) << 2) + c];
    }

    // Phase 2+3: compute embeddings in-register, masked coalesced stores
    const vfloat4 z = (vfloat4){0.0f, 0.0f, 0.0f, 0.0f};
#pragma unroll
    for (int r = 0; r < ROWS_PER_WAVE; ++r) {
        float v = fminf(fmaxf(frac[r] * ROI_IMG, 0.0f), ROI_IMG);
        const float pos = (float)(int)v;   // trunc toward 0, exact small int
        const float r0 = __builtin_amdgcn_fractf(pos * s0); // rev in [0,1)
        const float r1 = __builtin_amdgcn_fractf(pos * s1);
        vfloat4 e;
        e.x = __builtin_amdgcn_sinf(r0);   // sin(2pi*r0) = sin(pos*w0)
        e.y = __builtin_amdgcn_cosf(r0);   // cos
        e.z = __builtin_amdgcn_sinf(r1);
        e.w = __builtin_amdgcn_cosf(r1);
        out[(row0 + r) * 64 + lane] = (obj[r] == 1) ? e : z;
    }
}

extern "C" void kernel_launch(void* const* d_in, const int* in_sizes, int n_in,
                              void* d_out, int out_size, void* d_ws, size_t ws_size,
                              hipStream_t stream) {
    const float* bboxs = (const float*)d_in[0];   // [2048,128,4] fp32
    const int*   objs  = (const int*)d_in[1];     // [2048,128] int32
    const float* table = (const float*)d_in[2];   // [225,64] fp32 (unused)
    vfloat4* out = (vfloat4*)d_out;               // [262144*64] float4

    // waves = ROWS/4 = 65,536 ; blocks (4 waves each) = 16,384
    RoIBridge_kernel<<<ROI_ROWS / (ROWS_PER_WAVE * 4), 256, 0, stream>>>(
        bboxs, objs, table, out);
}

// Round 9
// 261.814 us; speedup vs baseline: 1.0362x; 1.0362x over previous
//
#include <hip/hip_runtime.h>

// RoIBridge: positional-embedding expansion per bbox coordinate, masked by
// obj_vec==1, dense [B*T, 256] fp32 output. B=2048, T=128, D=64, IMG=224.
//
// R9 (single variable vs R8): PERSISTENT grid-stride. 2048 blocks (8/CU,
// fully resident) x 8 iterations, with software-pipelined input prefetch:
// next iteration's obj/bbox loads issue before this iteration's stores, so
// the ~600-900 cyc cold input latency is hidden under the 268 MB store
// stream instead of being re-paid by 16K fire-and-exit blocks.
// Carries forward: ILP-4 rows/wave (R3-R5 sweep), in-register sinusoid via
// hw v_sin/v_cos in revolutions (R8, neutral vs OCML but fewer VGPRs).
//
// table[pos,i] = sin(pos * 10000^(-floor(i/2)/32)) even i, cos odd i.
// rev = fract(pos*scale/2pi): integer-revolution shift preserves sin/cos.
// absmax ~2e-3 vs 2e-2 threshold (verified R8).

#define ROI_ROWS  (2048 * 128)       // B*T = 262,144
#define ROI_IMG   224.0f
#define RPW       4                  // rows per wave-iteration
#define NGROUPS   (ROI_ROWS / RPW)   // 65,536
#define BLOCKS    2048               // 8 blocks/CU x 256 CUs -> resident
#define TOTAL_WAVES (BLOCKS * 4)     // 8,192
#define ITERS     (NGROUPS / TOTAL_WAVES)  // 8, exact

typedef float vfloat4 __attribute__((ext_vector_type(4)));

__global__ __launch_bounds__(256) void RoIBridge_kernel(
    const float* __restrict__ bboxs,   // [ROWS*4]
    const int*   __restrict__ objs,    // [ROWS]
    const float* __restrict__ table,   // unused (recomputed in-register)
    vfloat4*     __restrict__ out)     // [ROWS*64] float4s
{
    (void)table;
    const int gwave = blockIdx.x * 4 + (threadIdx.x >> 6);
    const int lane  = threadIdx.x & 63;
    const int c     = lane >> 4;       // coord 0..3 (16 lanes each)
    const int d4    = lane & 15;       // float4 within 64-float embedding

    // Per-thread frequency constants (revolutions per unit pos).
    const float L      = 0.41524101186092029f;   // log2(10000)/32
    const float INV2PI = 0.15915494309189535f;   // 1/(2pi)
    const float fi0 = (float)(d4 * 2);
    const float s0 = exp2f(-fi0 * L) * INV2PI;
    const float s1 = exp2f(-(fi0 + 1.0f) * L) * INV2PI;

    int   obj[RPW];
    float frac[RPW];
    int   row0 = gwave * RPW;

    // Prologue: load first iteration's inputs
#pragma unroll
    for (int r = 0; r < RPW; ++r) {
        obj[r]  = objs[row0 + r];
        frac[r] = bboxs[((row0 + r) << 2) + c];
    }

    const vfloat4 z = (vfloat4){0.0f, 0.0f, 0.0f, 0.0f};

#pragma unroll
    for (int it = 0; it < ITERS; ++it) {
        // Prefetch next iteration's inputs (independent of current stores)
        const int nrow0 = row0 + TOTAL_WAVES * RPW;
        int   nobj[RPW];
        float nfrac[RPW];
        if (it < ITERS - 1) {
#pragma unroll
            for (int r = 0; r < RPW; ++r) {
                nobj[r]  = objs[nrow0 + r];
                nfrac[r] = bboxs[((nrow0 + r) << 2) + c];
            }
        }

        // Compute + store current iteration
#pragma unroll
        for (int r = 0; r < RPW; ++r) {
            float v = fminf(fmaxf(frac[r] * ROI_IMG, 0.0f), ROI_IMG);
            const float pos = (float)(int)v;        // trunc, exact small int
            const float r0 = __builtin_amdgcn_fractf(pos * s0);
            const float r1 = __builtin_amdgcn_fractf(pos * s1);
            vfloat4 e;
            e.x = __builtin_amdgcn_sinf(r0);
            e.y = __builtin_amdgcn_cosf(r0);
            e.z = __builtin_amdgcn_sinf(r1);
            e.w = __builtin_amdgcn_cosf(r1);
            out[(row0 + r) * 64 + lane] = (obj[r] == 1) ? e : z;
        }

        if (it < ITERS - 1) {
#pragma unroll
            for (int r = 0; r < RPW; ++r) {
                obj[r]  = nobj[r];
                frac[r] = nfrac[r];
            }
            row0 = nrow0;
        }
    }
}

extern "C" void kernel_launch(void* const* d_in, const int* in_sizes, int n_in,
                              void* d_out, int out_size, void* d_ws, size_t ws_size,
                              hipStream_t stream) {
    const float* bboxs = (const float*)d_in[0];   // [2048,128,4] fp32
    const int*   objs  = (const int*)d_in[1];     // [2048,128] int32
    const float* table = (const float*)d_in[2];   // [225,64] fp32 (unused)
    vfloat4* out = (vfloat4*)d_out;               // [262144*64] float4

    RoIBridge_kernel<<<BLOCKS, 256, 0, stream>>>(bboxs, objs, table, out);
}